// Round 1
// baseline (109.593 us; speedup 1.0000x reference)
//
#include <hip/hip_runtime.h>

constexpr int B  = 16384;
constexpr int D  = 64;
constexpr int LA = 20;
constexpr int LC = 5;
constexpr int SPLIT = 16;   // artists handled by the role-A wave; role-B gets LA-SPLIT

// DPP row-rotate-and-add: v += rotate_right_within_16lane_row(v, N).
template <int CTRL>
__device__ __forceinline__ float ror_add(float v) {
    const int r = __builtin_amdgcn_update_dpp(
        0, __float_as_int(v), CTRL, 0xF, 0xF, true);
    return v + __int_as_float(r);
}

// Reduce N independent values across a 16-lane row, stage-interleaved for ILP.
template <int N>
__device__ __forceinline__ void reduce16(float (&p)[N]) {
    #pragma unroll
    for (int l = 0; l < N; ++l) p[l] = ror_add<0x128>(p[l]);  // ror 8
    #pragma unroll
    for (int l = 0; l < N; ++l) p[l] = ror_add<0x124>(p[l]);  // ror 4
    #pragma unroll
    for (int l = 0; l < N; ++l) p[l] = ror_add<0x122>(p[l]);  // ror 2
    #pragma unroll
    for (int l = 0; l < N; ++l) p[l] = ror_add<0x121>(p[l]);  // ror 1
}

// Pair-of-waves per 4 rows: even wave (A) = artists 0..15; odd wave (B) =
// artists 16..19 + categories + softmax + epilogue. Doubles wave count
// (16 -> 32 waves/CU possible) and halves each wave's dependent-load chain.
__global__ __launch_bounds__(512, 8) void aspect_kernel(
    const int*   __restrict__ user_id,
    const int*   __restrict__ artists_id,
    const int*   __restrict__ categories_id,
    const float* __restrict__ user_factors,
    const float* __restrict__ entity_factors,
    const float* __restrict__ relation_k,
    float*       __restrict__ out)
{
    const int tid  = threadIdx.x;
    const int lane = tid & 63;
    const int sl   = lane & 15;      // sub-lane within 16-lane group (DPP row)
    const int grp  = lane >> 4;      // row-group within wave (0..3)
    const int wid  = tid >> 6;       // wave id within block (0..7)
    const int half = wid & 1;        // 0 = role A, 1 = role B
    const int rowInBlk = (wid >> 1) * 4 + grp;     // 0..15
    const int b = (blockIdx.x << 4) + rowInBlk;    // 1024 blocks * 16 rows == B

    __shared__ float s_partA[16];    // per-row partial sum from role-A wave

    // Output layout: prediction(B) | scores(B*3) | c_act(B) | c_dir(B) | niubi_act(B*LA) | niubi_dir(B*LC)
    float* pred    = out;
    float* scores  = out + B;
    float* c_act_o = out + (size_t)4 * B;
    float* c_dir_o = out + (size_t)5 * B;
    float* niubiA  = out + (size_t)6 * B;
    float* niubiC  = niubiA + (size_t)B * LA;

    const int    uid = user_id[b];
    const float4 u4  = *(const float4*)&user_factors[(size_t)uid * D + sl * 4];

    float sumB = 0.f, sumC = 0.f, s0 = 0.f, s1 = 0.f, s2 = 0.f;

    if (half == 0) {
        // ---- role A: artists 0..15 ----
        float pa[SPLIT];
        #pragma unroll
        for (int l = 0; l < SPLIT; ++l) {
            const int    idx = artists_id[b * LA + l];
            const float4 e   = *(const float4*)&entity_factors[(size_t)idx * D + sl * 4];
            pa[l] = fmaf(e.x, u4.x, fmaf(e.y, u4.y, fmaf(e.z, u4.z, e.w * u4.w)));
        }
        reduce16(pa);
        // niubi_act[0..15]: lanes 0..3 each store one float4 (b*80B is 16B-aligned)
        if (sl < 4) {
            float4 v;
            v.x = sl == 0 ? pa[0] : sl == 1 ? pa[4] : sl == 2 ? pa[8]  : pa[12];
            v.y = sl == 0 ? pa[1] : sl == 1 ? pa[5] : sl == 2 ? pa[9]  : pa[13];
            v.z = sl == 0 ? pa[2] : sl == 1 ? pa[6] : sl == 2 ? pa[10] : pa[14];
            v.w = sl == 0 ? pa[3] : sl == 1 ? pa[7] : sl == 2 ? pa[11] : pa[15];
            *(float4*)&niubiA[(size_t)b * LA + sl * 4] = v;
        }
        float part = 0.f;
        #pragma unroll
        for (int l = 0; l < SPLIT; ++l) part += pa[l];
        if (sl == 0) s_partA[rowInBlk] = part;
    } else {
        // ---- role B: artists 16..19, categories, softmax, epilogue prep ----
        float pa[LA - SPLIT];
        #pragma unroll
        for (int l = 0; l < LA - SPLIT; ++l) {
            const int    idx = artists_id[b * LA + SPLIT + l];
            const float4 e   = *(const float4*)&entity_factors[(size_t)idx * D + sl * 4];
            pa[l] = fmaf(e.x, u4.x, fmaf(e.y, u4.y, fmaf(e.z, u4.z, e.w * u4.w)));
        }
        float pc[LC];
        #pragma unroll
        for (int l = 0; l < LC; ++l) {
            const int    idx = categories_id[b * LC + l];
            const float4 e   = *(const float4*)&entity_factors[(size_t)idx * D + sl * 4];
            pc[l] = fmaf(e.x, u4.x, fmaf(e.y, u4.y, fmaf(e.z, u4.z, e.w * u4.w)));
        }

        // users @ relation_k (D x 3), leaky_relu, softmax over 3
        float ps[3];
        {
            const int d0 = sl * 4;
            ps[0] = fmaf(u4.x, relation_k[(d0+0)*3+0], fmaf(u4.y, relation_k[(d0+1)*3+0],
                    fmaf(u4.z, relation_k[(d0+2)*3+0], u4.w * relation_k[(d0+3)*3+0])));
            ps[1] = fmaf(u4.x, relation_k[(d0+0)*3+1], fmaf(u4.y, relation_k[(d0+1)*3+1],
                    fmaf(u4.z, relation_k[(d0+2)*3+1], u4.w * relation_k[(d0+3)*3+1])));
            ps[2] = fmaf(u4.x, relation_k[(d0+0)*3+2], fmaf(u4.y, relation_k[(d0+1)*3+2],
                    fmaf(u4.z, relation_k[(d0+2)*3+2], u4.w * relation_k[(d0+3)*3+2])));
        }
        reduce16(ps);
        const float q0 = ps[0] >= 0.f ? ps[0] : 0.2f * ps[0];
        const float q1 = ps[1] >= 0.f ? ps[1] : 0.2f * ps[1];
        const float q2 = ps[2] >= 0.f ? ps[2] : 0.2f * ps[2];
        const float m   = fmaxf(q0, fmaxf(q1, q2));
        const float e0  = __expf(q0 - m), e1 = __expf(q1 - m), e2 = __expf(q2 - m);
        const float inv = 1.f / (e0 + e1 + e2);
        s0 = e0 * inv; s1 = e1 * inv; s2 = e2 * inv;

        reduce16(pa);
        reduce16(pc);

        // niubi_act[16..19]: one float4 from lane 0 (b*80B + 64B is 16B-aligned)
        if (sl == 0) {
            float4 v; v.x = pa[0]; v.y = pa[1]; v.z = pa[2]; v.w = pa[3];
            *(float4*)&niubiA[(size_t)b * LA + SPLIT] = v;
        }
        if (sl < LC) {
            const float v = sl == 0 ? pc[0] : sl == 1 ? pc[1] : sl == 2 ? pc[2] : sl == 3 ? pc[3] : pc[4];
            niubiC[(size_t)b * LC + sl] = v;
        }
        if (sl < 3) {
            const float v = sl == 0 ? s0 : sl == 1 ? s1 : s2;
            scores[b * 3 + sl] = v;
        }
        #pragma unroll
        for (int l = 0; l < LA - SPLIT; ++l) sumB += pa[l];
        #pragma unroll
        for (int l = 0; l < LC; ++l) sumC += pc[l];
    }

    __syncthreads();   // uniform barrier: every wave reaches exactly one

    if (half == 1 && sl == 0) {
        const float sumA  = s_partA[rowInBlk] + sumB;
        const float c_act = sumA * (1.f / LA);
        const float c_dir = sumC * (1.f / LC);
        pred[b]    = (c_act * s0 + c_dir * s1) / (s0 + s1);
        c_act_o[b] = c_act;
        c_dir_o[b] = c_dir;
    }
}

extern "C" void kernel_launch(void* const* d_in, const int* in_sizes, int n_in,
                              void* d_out, int out_size, void* d_ws, size_t ws_size,
                              hipStream_t stream) {
    const int*   user_id        = (const int*)d_in[0];
    const int*   artists_id     = (const int*)d_in[1];
    const int*   categories_id  = (const int*)d_in[2];
    // d_in[3] = rate (unused scalar)
    const float* user_factors   = (const float*)d_in[4];
    const float* entity_factors = (const float*)d_in[5];
    const float* relation_k     = (const float*)d_in[6];
    float*       out            = (float*)d_out;

    const int rows_per_block = 16;            // 16 rows, 2 waves per 4 rows = 512 threads
    const int grid = B / rows_per_block;      // 1024
    aspect_kernel<<<grid, 512, 0, stream>>>(
        user_id, artists_id, categories_id, user_factors, entity_factors, relation_k, out);
}

// Round 2
// 103.547 us; speedup vs baseline: 1.0584x; 1.0584x over previous
//
#include <hip/hip_runtime.h>

constexpr int B  = 16384;
constexpr int D  = 64;
constexpr int LA = 20;
constexpr int LC = 5;

// DPP row-rotate-and-add: v += rotate_right_within_16lane_row(v, N).
template <int CTRL>
__device__ __forceinline__ float ror_add(float v) {
    const int r = __builtin_amdgcn_update_dpp(
        0, __float_as_int(v), CTRL, 0xF, 0xF, true);
    return v + __int_as_float(r);
}

// Reduce N independent values across a 16-lane row, stage-interleaved for ILP.
template <int N>
__device__ __forceinline__ void reduce16(float (&p)[N]) {
    #pragma unroll
    for (int l = 0; l < N; ++l) p[l] = ror_add<0x128>(p[l]);  // ror 8
    #pragma unroll
    for (int l = 0; l < N; ++l) p[l] = ror_add<0x124>(p[l]);  // ror 4
    #pragma unroll
    for (int l = 0; l < N; ++l) p[l] = ror_add<0x122>(p[l]);  // ror 2
    #pragma unroll
    for (int l = 0; l < N; ++l) p[l] = ror_add<0x121>(p[l]);  // ror 1
}

// Broadcast lane K (0..15) of each 16-lane row to all lanes of that row.
// BitMode swizzle: src = (lane & 0x10) | K  (bit4 kept -> row-local broadcast).
template <int K>
__device__ __forceinline__ int bcast16(int v) {
    return __builtin_amdgcn_ds_swizzle(v, (K << 5) | 0x10);
}

// 16 lanes per batch row, each lane holds 4 dims (float4). 16 rows per block.
// Indices are fetched cooperatively (2 VMEM ops) and broadcast in-register,
// so all 25 entity gathers issue back-to-back with no index round-trips.
__global__ __launch_bounds__(256, 4) void aspect_kernel(
    const int*   __restrict__ user_id,
    const int*   __restrict__ artists_id,
    const int*   __restrict__ categories_id,
    const float* __restrict__ user_factors,
    const float* __restrict__ entity_factors,
    const float* __restrict__ relation_k,
    float*       __restrict__ out)
{
    const int tid = threadIdx.x;
    const int sl  = tid & 15;        // sub-lane within 16-lane group (DPP row)
    const int grp = tid >> 4;        // group index within block (0..15)
    const int b   = (blockIdx.x << 4) + grp;   // 1024 blocks * 16 rows == B

    // Output layout: prediction(B) | scores(B*3) | c_act(B) | c_dir(B) | niubi_act(B*LA) | niubi_dir(B*LC)
    float* pred    = out;
    float* scores  = out + B;
    float* c_act_o = out + (size_t)4 * B;
    float* c_dir_o = out + (size_t)5 * B;
    float* niubiA  = out + (size_t)6 * B;
    float* niubiC  = niubiA + (size_t)B * LA;

    // ---- cooperative index fetch: lanes 0..4 of each row carry all 25 ids ----
    int4 av = {0, 0, 0, 0};
    int  cvl = 0;
    if (sl < 5) {
        av  = *(const int4*)&artists_id[b * LA + sl * 4];   // b*80B is 16B-aligned
        cvl = categories_id[b * LC + sl];
    }
    const int    uid = user_id[b];
    const float4 u4  = *(const float4*)&user_factors[(size_t)uid * D + sl * 4];

    // ---- in-register broadcast of indices to all 16 lanes of the row ----
    int ai[LA], ci[LC];
    #define BA(l) ai[l] = bcast16<((l) >> 2)>( \
        ((l) & 3) == 0 ? av.x : ((l) & 3) == 1 ? av.y : ((l) & 3) == 2 ? av.z : av.w);
    BA(0)  BA(1)  BA(2)  BA(3)  BA(4)  BA(5)  BA(6)  BA(7)  BA(8)  BA(9)
    BA(10) BA(11) BA(12) BA(13) BA(14) BA(15) BA(16) BA(17) BA(18) BA(19)
    #undef BA
    ci[0] = bcast16<0>(cvl); ci[1] = bcast16<1>(cvl); ci[2] = bcast16<2>(cvl);
    ci[3] = bcast16<3>(cvl); ci[4] = bcast16<4>(cvl);

    // ---- issue all 25 entity gathers (dot products consume on arrival) ----
    float pa[LA];
    #pragma unroll
    for (int l = 0; l < LA; ++l) {
        const float4 e = *(const float4*)&entity_factors[(size_t)ai[l] * D + sl * 4];
        pa[l] = fmaf(e.x, u4.x, fmaf(e.y, u4.y, fmaf(e.z, u4.z, e.w * u4.w)));
    }
    float pc[LC];
    #pragma unroll
    for (int l = 0; l < LC; ++l) {
        const float4 e = *(const float4*)&entity_factors[(size_t)ci[l] * D + sl * 4];
        pc[l] = fmaf(e.x, u4.x, fmaf(e.y, u4.y, fmaf(e.z, u4.z, e.w * u4.w)));
    }

    // ---- users @ relation_k, leaky_relu, softmax (VALU work in miss shadow) ----
    float ps[3];
    {
        const int d0 = sl * 4;
        ps[0] = fmaf(u4.x, relation_k[(d0+0)*3+0], fmaf(u4.y, relation_k[(d0+1)*3+0],
                fmaf(u4.z, relation_k[(d0+2)*3+0], u4.w * relation_k[(d0+3)*3+0])));
        ps[1] = fmaf(u4.x, relation_k[(d0+0)*3+1], fmaf(u4.y, relation_k[(d0+1)*3+1],
                fmaf(u4.z, relation_k[(d0+2)*3+1], u4.w * relation_k[(d0+3)*3+1])));
        ps[2] = fmaf(u4.x, relation_k[(d0+0)*3+2], fmaf(u4.y, relation_k[(d0+1)*3+2],
                fmaf(u4.z, relation_k[(d0+2)*3+2], u4.w * relation_k[(d0+3)*3+2])));
    }
    reduce16(ps);
    const float q0 = ps[0] >= 0.f ? ps[0] : 0.2f * ps[0];
    const float q1 = ps[1] >= 0.f ? ps[1] : 0.2f * ps[1];
    const float q2 = ps[2] >= 0.f ? ps[2] : 0.2f * ps[2];
    const float m   = fmaxf(q0, fmaxf(q1, q2));
    const float e0  = __expf(q0 - m), e1 = __expf(q1 - m), e2 = __expf(q2 - m);
    const float inv = 1.f / (e0 + e1 + e2);
    const float s0 = e0 * inv, s1 = e1 * inv, s2 = e2 * inv;

    // ---- reductions ----
    reduce16(pa);
    float sumA = 0.f;
    #pragma unroll
    for (int l = 0; l < LA; ++l) sumA += pa[l];
    const float c_act = sumA * (1.f / LA);

    reduce16(pc);
    float sumC = 0.f;
    #pragma unroll
    for (int l = 0; l < LC; ++l) sumC += pc[l];
    const float c_dir = sumC * (1.f / LC);

    // ---- stores (all lanes in group hold all reduced values) ----
    if (sl < 5) {
        float4 v;
        v.x = sl == 0 ? pa[0] : sl == 1 ? pa[4]  : sl == 2 ? pa[8]  : sl == 3 ? pa[12] : pa[16];
        v.y = sl == 0 ? pa[1] : sl == 1 ? pa[5]  : sl == 2 ? pa[9]  : sl == 3 ? pa[13] : pa[17];
        v.z = sl == 0 ? pa[2] : sl == 1 ? pa[6]  : sl == 2 ? pa[10] : sl == 3 ? pa[14] : pa[18];
        v.w = sl == 0 ? pa[3] : sl == 1 ? pa[7]  : sl == 2 ? pa[11] : sl == 3 ? pa[15] : pa[19];
        *(float4*)&niubiA[(size_t)b * LA + sl * 4] = v;
    }
    if (sl < LC) {
        const float v = sl == 0 ? pc[0] : sl == 1 ? pc[1] : sl == 2 ? pc[2] : sl == 3 ? pc[3] : pc[4];
        niubiC[(size_t)b * LC + sl] = v;
    }
    if (sl < 3) {
        const float v = sl == 0 ? s0 : sl == 1 ? s1 : s2;
        scores[b * 3 + sl] = v;
    }
    if (sl == 0) {
        pred[b]    = (c_act * s0 + c_dir * s1) / (s0 + s1);
        c_act_o[b] = c_act;
        c_dir_o[b] = c_dir;
    }
}

extern "C" void kernel_launch(void* const* d_in, const int* in_sizes, int n_in,
                              void* d_out, int out_size, void* d_ws, size_t ws_size,
                              hipStream_t stream) {
    const int*   user_id        = (const int*)d_in[0];
    const int*   artists_id     = (const int*)d_in[1];
    const int*   categories_id  = (const int*)d_in[2];
    // d_in[3] = rate (unused scalar)
    const float* user_factors   = (const float*)d_in[4];
    const float* entity_factors = (const float*)d_in[5];
    const float* relation_k     = (const float*)d_in[6];
    float*       out            = (float*)d_out;

    const int rows_per_block = 16;               // 16 groups of 16 lanes = 256 threads
    const int grid = B / rows_per_block;         // 1024
    aspect_kernel<<<grid, 256, 0, stream>>>(
        user_id, artists_id, categories_id, user_factors, entity_factors, relation_k, out);
}